// Round 5
// baseline (518.808 us; speedup 1.0000x reference)
//
#include <hip/hip_runtime.h>
#include <hip/hip_bf16.h>

typedef __hip_bfloat16 bf16;
typedef short bf16x8 __attribute__((ext_vector_type(8)));
typedef float f32x4  __attribute__((ext_vector_type(4)));

#define ROWS 53176    // B * L_TOTAL
#define LTOT 13294

__device__ __forceinline__ float b2f(bf16 v) { return __bfloat162float(v); }

__device__ __forceinline__ void gl2lds16(const void* g, void* l) {
    __builtin_amdgcn_global_load_lds(
        (const __attribute__((address_space(1))) unsigned*)g,
        (__attribute__((address_space(3))) unsigned*)l, 16, 0, 0);
}

// ============ narrow MFMA GEMM: 128x128 tile, 2-phase double-buffered ============
template<bool RELU>
__global__ __launch_bounds__(256)
void mfma_gemm_n(const bf16* __restrict__ A, const bf16* __restrict__ Bt,
                 const float* __restrict__ bias, bf16* __restrict__ C,
                 int M, int N, int K)
{
    __shared__ __align__(16) short As[2][128 * 32];
    __shared__ __align__(16) short Bs[2][128 * 32];
    const int tid  = threadIdx.x;
    const int wave = tid >> 6, lane = tid & 63;

    const int nwg  = gridDim.x * gridDim.y;
    const int orig = blockIdx.y * gridDim.x + blockIdx.x;
    const int wgid = ((nwg & 7) == 0) ? ((orig & 7) * (nwg >> 3) + (orig >> 3)) : orig;
    const int bx = wgid % gridDim.x, by = wgid / gridDim.x;

    const int m0 = by * 128, n0 = bx * 128;
    const int lrow = lane >> 2, lcol = lane & 3;
    const int quad = lane >> 4, l15 = lane & 15;

    f32x4 acc[4][4];
#pragma unroll
    for (int i = 0; i < 4; ++i)
#pragma unroll
        for (int j = 0; j < 4; ++j) acc[i][j] = (f32x4){0.f, 0.f, 0.f, 0.f};

    const int wM = (wave >> 1) * 64, wN = (wave & 1) * 64;

    auto stage = [&](int p, int kk) {
#pragma unroll
        for (int q = 0; q < 2; ++q) {
            int rbase = wave * 32 + q * 16;
            int row = rbase + lrow;
            int sw = (lcol * 16) ^ ((row & 3) << 4);     // source pre-swizzle
            gl2lds16((const char*)(A  + (size_t)(m0 + row) * K + kk) + sw, &As[p][rbase * 32]);
            gl2lds16((const char*)(Bt + (size_t)(n0 + row) * K + kk) + sw, &Bs[p][rbase * 32]);
        }
    };

    auto compute = [&](int p) {
        bf16x8 af[4], bfr[4];
#pragma unroll
        for (int i = 0; i < 4; ++i) {
            int row = wM + i * 16 + l15;
            af[i] = *(const bf16x8*)((const char*)&As[p][row * 32]
                                     + ((quad * 16) ^ ((row & 3) << 4)));
        }
#pragma unroll
        for (int j = 0; j < 4; ++j) {
            int row = wN + j * 16 + l15;
            bfr[j] = *(const bf16x8*)((const char*)&Bs[p][row * 32]
                                      + ((quad * 16) ^ ((row & 3) << 4)));
        }
#pragma unroll
        for (int i = 0; i < 4; ++i)
#pragma unroll
            for (int j = 0; j < 4; ++j)
                acc[i][j] = __builtin_amdgcn_mfma_f32_16x16x32_bf16(bfr[j], af[i], acc[i][j], 0, 0, 0);
    };

    stage(0, 0);
    __syncthreads();
    int p = 0;
    for (int kk = 32; kk < K; kk += 32) {
        stage(p ^ 1, kk);
        compute(p);
        __syncthreads();
        p ^= 1;
    }
    compute(p);

    float4 b4[4];
#pragma unroll
    for (int j = 0; j < 4; ++j)
        b4[j] = *(const float4*)&bias[n0 + wN + j * 16 + quad * 4];

#pragma unroll
    for (int i = 0; i < 4; ++i) {
        int gm = m0 + wM + i * 16 + l15;
        if (gm >= M) continue;
#pragma unroll
        for (int j = 0; j < 4; ++j) {
            int gn = n0 + wN + j * 16 + quad * 4;
            union { bf16 h[4]; uint2 u2; } pk;
#pragma unroll
            for (int r = 0; r < 4; ++r) {
                float v = acc[i][j][r] + ((const float*)&b4[j])[r];
                if (RELU) v = fmaxf(v, 0.f);
                pk.h[r] = __float2bfloat16(v);
            }
            *(uint2*)&C[(size_t)gm * N + gn] = pk.u2;
        }
    }
}

// ============ fused val+cat GEMM: bx<2 -> v (head-major layout), bx>=2 -> ocat ==
__global__ __launch_bounds__(256)
void mfma_gemm_vc(const bf16* __restrict__ Av, const bf16* __restrict__ Aq,
                  const bf16* __restrict__ Bv, const bf16* __restrict__ Bc,
                  const float* __restrict__ bv, const float* __restrict__ bc,
                  bf16* __restrict__ Cv, bf16* __restrict__ Cc, int M)
{
    __shared__ __align__(16) short As[2][128 * 32];
    __shared__ __align__(16) short Bs[2][128 * 32];
    const int tid  = threadIdx.x;
    const int wave = tid >> 6, lane = tid & 63;
    const int K = 256;

    const int nwg  = gridDim.x * gridDim.y;   // 5*416 = 2080, div by 8
    const int orig = blockIdx.y * gridDim.x + blockIdx.x;
    const int wgid = ((nwg & 7) == 0) ? ((orig & 7) * (nwg >> 3) + (orig >> 3)) : orig;
    const int bx = wgid % gridDim.x, by = wgid / gridDim.x;

    const bool isval = bx < 2;
    const bf16* A    = isval ? Av : Aq;
    const bf16* Bt   = isval ? Bv : Bc;
    const float* bias = isval ? bv : bc;
    const int n0 = isval ? bx * 128 : (bx - 2) * 128;

    const int m0 = by * 128;
    const int lrow = lane >> 2, lcol = lane & 3;
    const int quad = lane >> 4, l15 = lane & 15;

    f32x4 acc[4][4];
#pragma unroll
    for (int i = 0; i < 4; ++i)
#pragma unroll
        for (int j = 0; j < 4; ++j) acc[i][j] = (f32x4){0.f, 0.f, 0.f, 0.f};

    const int wM = (wave >> 1) * 64, wN = (wave & 1) * 64;

    auto stage = [&](int p, int kk) {
#pragma unroll
        for (int q = 0; q < 2; ++q) {
            int rbase = wave * 32 + q * 16;
            int row = rbase + lrow;
            int sw = (lcol * 16) ^ ((row & 3) << 4);
            gl2lds16((const char*)(A  + (size_t)(m0 + row) * K + kk) + sw, &As[p][rbase * 32]);
            gl2lds16((const char*)(Bt + (size_t)(n0 + row) * K + kk) + sw, &Bs[p][rbase * 32]);
        }
    };

    auto compute = [&](int p) {
        bf16x8 af[4], bfr[4];
#pragma unroll
        for (int i = 0; i < 4; ++i) {
            int row = wM + i * 16 + l15;
            af[i] = *(const bf16x8*)((const char*)&As[p][row * 32]
                                     + ((quad * 16) ^ ((row & 3) << 4)));
        }
#pragma unroll
        for (int j = 0; j < 4; ++j) {
            int row = wN + j * 16 + l15;
            bfr[j] = *(const bf16x8*)((const char*)&Bs[p][row * 32]
                                      + ((quad * 16) ^ ((row & 3) << 4)));
        }
#pragma unroll
        for (int i = 0; i < 4; ++i)
#pragma unroll
            for (int j = 0; j < 4; ++j)
                acc[i][j] = __builtin_amdgcn_mfma_f32_16x16x32_bf16(bfr[j], af[i], acc[i][j], 0, 0, 0);
    };

    stage(0, 0);
    __syncthreads();
    int p = 0;
    for (int kk = 32; kk < K; kk += 32) {
        stage(p ^ 1, kk);
        compute(p);
        __syncthreads();
        p ^= 1;
    }
    compute(p);

    float4 b4[4];
#pragma unroll
    for (int j = 0; j < 4; ++j)
        b4[j] = *(const float4*)&bias[n0 + wN + j * 16 + quad * 4];

#pragma unroll
    for (int i = 0; i < 4; ++i) {
        int gm = m0 + wM + i * 16 + l15;
        if (gm >= M) continue;
        int b   = gm / LTOT;                 // magic-mul div
        int pix = gm - b * LTOT;
#pragma unroll
        for (int j = 0; j < 4; ++j) {
            int gn = n0 + wN + j * 16 + quad * 4;
            union { bf16 h[4]; uint2 u2; } pk;
#pragma unroll
            for (int r = 0; r < 4; ++r)
                pk.h[r] = __float2bfloat16(acc[i][j][r] + ((const float*)&b4[j])[r]);
            if (isval) {
                // v layout: [b][head][pix][ch]  (pixel stride 64 B)
                int head = gn >> 5, ch = gn & 31;
                size_t idx = ((size_t)(b * 8 + head) * LTOT + pix) * 32 + ch;
                *(uint2*)&Cv[idx] = pk.u2;
            } else {
                *(uint2*)&Cc[(size_t)gm * 384 + gn] = pk.u2;
            }
        }
    }
}

// ============ wide MFMA GEMM with fused LayerNorm: 128x256, 512 thr, dbuf ======
template<typename OT>
__global__ __launch_bounds__(512)
void mfma_gemm_ln(const bf16* __restrict__ A, const bf16* __restrict__ Bt,
                  const float* __restrict__ bias, const bf16* __restrict__ res,
                  OT* __restrict__ C, const float* __restrict__ gam,
                  const float* __restrict__ bet, int M, int K)
{
    __shared__ __align__(16) short As[2][128 * 32];
    __shared__ __align__(16) short Bs[2][256 * 32];
    __shared__ float rsum[128], rsq[128];
    const int tid  = threadIdx.x;
    const int wave = tid >> 6, lane = tid & 63;
    const int m0 = blockIdx.x * 128;
    const int lrow = lane >> 2, lcol = lane & 3;
    const int quad = lane >> 4, l15 = lane & 15;
    if (tid < 128) { rsum[tid] = 0.f; rsq[tid] = 0.f; }

    f32x4 acc[4][4];
#pragma unroll
    for (int i = 0; i < 4; ++i)
#pragma unroll
        for (int j = 0; j < 4; ++j) acc[i][j] = (f32x4){0.f, 0.f, 0.f, 0.f};

    const int wM = (wave >> 2) * 64, wN = (wave & 3) * 64;

    auto stage = [&](int p, int kk) {
#pragma unroll
        for (int q = 0; q < 3; ++q) {
            int r = wave * 48 + q * 16;
            int sw;
            if (r < 128) {
                int row = r + lrow;
                sw = (lcol * 16) ^ ((row & 3) << 4);
                gl2lds16((const char*)(A + (size_t)(m0 + row) * K + kk) + sw, &As[p][r * 32]);
            } else {
                int rr = r - 128;
                int row = rr + lrow;
                sw = (lcol * 16) ^ ((row & 3) << 4);
                gl2lds16((const char*)(Bt + (size_t)(row) * K + kk) + sw, &Bs[p][rr * 32]);
            }
        }
    };

    auto compute = [&](int p) {
        bf16x8 af[4], bfr[4];
#pragma unroll
        for (int i = 0; i < 4; ++i) {
            int row = wM + i * 16 + l15;
            af[i] = *(const bf16x8*)((const char*)&As[p][row * 32]
                                     + ((quad * 16) ^ ((row & 3) << 4)));
        }
#pragma unroll
        for (int j = 0; j < 4; ++j) {
            int row = wN + j * 16 + l15;
            bfr[j] = *(const bf16x8*)((const char*)&Bs[p][row * 32]
                                      + ((quad * 16) ^ ((row & 3) << 4)));
        }
#pragma unroll
        for (int i = 0; i < 4; ++i)
#pragma unroll
            for (int j = 0; j < 4; ++j)
                acc[i][j] = __builtin_amdgcn_mfma_f32_16x16x32_bf16(bfr[j], af[i], acc[i][j], 0, 0, 0);
    };

    stage(0, 0);
    __syncthreads();
    int p = 0;
    for (int kk = 32; kk < K; kk += 32) {
        stage(p ^ 1, kk);
        compute(p);
        __syncthreads();
        p ^= 1;
    }
    compute(p);

    float4 b4[4], g4[4], be4[4];
#pragma unroll
    for (int j = 0; j < 4; ++j) {
        int gn = wN + j * 16 + quad * 4;
        b4[j]  = *(const float4*)&bias[gn];
        g4[j]  = *(const float4*)&gam[gn];
        be4[j] = *(const float4*)&bet[gn];
    }

    float lsum[4], lsq[4];
#pragma unroll
    for (int i = 0; i < 4; ++i) {
        int gm = m0 + wM + i * 16 + l15;
        lsum[i] = 0.f; lsq[i] = 0.f;
#pragma unroll
        for (int j = 0; j < 4; ++j) {
            int gn = wN + j * 16 + quad * 4;
            float r4[4] = {0.f, 0.f, 0.f, 0.f};
            if (gm < M) {
                uint2 ru = *(const uint2*)&res[(size_t)gm * 256 + gn];
                const bf16* rh = (const bf16*)&ru;
#pragma unroll
                for (int r = 0; r < 4; ++r) r4[r] = b2f(rh[r]);
            }
#pragma unroll
            for (int r = 0; r < 4; ++r) {
                float v = acc[i][j][r] + ((const float*)&b4[j])[r] + r4[r];
                acc[i][j][r] = v;
                lsum[i] += v;
                lsq[i]  += v * v;
            }
        }
#pragma unroll
        for (int mask = 16; mask <= 32; mask <<= 1) {
            lsum[i] += __shfl_xor(lsum[i], mask);
            lsq[i]  += __shfl_xor(lsq[i], mask);
        }
    }
    if (quad == 0) {
#pragma unroll
        for (int i = 0; i < 4; ++i) {
            atomicAdd(&rsum[wM + i * 16 + l15], lsum[i]);
            atomicAdd(&rsq [wM + i * 16 + l15], lsq[i]);
        }
    }
    __syncthreads();

#pragma unroll
    for (int i = 0; i < 4; ++i) {
        int lr = wM + i * 16 + l15;
        int gm = m0 + lr;
        if (gm >= M) continue;
        float mean = rsum[lr] * (1.f / 256.f);
        float var  = rsq[lr] * (1.f / 256.f) - mean * mean;
        float rstd = rsqrtf(fmaxf(var, 0.f) + 1e-5f);
#pragma unroll
        for (int j = 0; j < 4; ++j) {
            int gn = wN + j * 16 + quad * 4;
            if constexpr (sizeof(OT) == 2) {
                union { bf16 h[4]; uint2 u2; } pk;
#pragma unroll
                for (int r = 0; r < 4; ++r)
                    pk.h[r] = __float2bfloat16((acc[i][j][r] - mean) * rstd *
                              ((const float*)&g4[j])[r] + ((const float*)&be4[j])[r]);
                *(uint2*)&((bf16*)C)[(size_t)gm * 256 + gn] = pk.u2;
            } else {
                float4 o;
#pragma unroll
                for (int r = 0; r < 4; ++r)
                    ((float*)&o)[r] = (acc[i][j][r] - mean) * rstd *
                              ((const float*)&g4[j])[r] + ((const float*)&be4[j])[r];
                *(float4*)&((float*)C)[(size_t)gm * 256 + gn] = o;
            }
        }
    }
}

// ============ fused casts: src/pos -> bf16, weights -> bf16 (one dispatch) =====
__global__ __launch_bounds__(256)
void cast_all(const float* __restrict__ s, const float* __restrict__ p,
              bf16* __restrict__ sb, bf16* __restrict__ qb,
              const float* __restrict__ Wval, const float* __restrict__ Woff,
              const float* __restrict__ Wattn, const float* __restrict__ Wout,
              const float* __restrict__ W1, const float* __restrict__ W2,
              const float* __restrict__ boff, const float* __restrict__ battn,
              bf16* __restrict__ Wval_t, bf16* __restrict__ Wcat_t,
              bf16* __restrict__ Wout_t, bf16* __restrict__ W1_t,
              bf16* __restrict__ W2_t, float* __restrict__ bcat)
{
    const int blk = blockIdx.x;
    if (blk < 13294) {
        int i = blk * 256 + threadIdx.x;
        float4 sv = ((const float4*)s)[i];
        float4 pv = ((const float4*)p)[i];
        union { bf16 h[4]; uint2 u; } a, b;
        a.h[0] = __float2bfloat16(sv.x); a.h[1] = __float2bfloat16(sv.y);
        a.h[2] = __float2bfloat16(sv.z); a.h[3] = __float2bfloat16(sv.w);
        b.h[0] = __float2bfloat16(sv.x + pv.x); b.h[1] = __float2bfloat16(sv.y + pv.y);
        b.h[2] = __float2bfloat16(sv.z + pv.z); b.h[3] = __float2bfloat16(sv.w + pv.w);
        ((uint2*)sb)[i] = a.u;
        ((uint2*)qb)[i] = b.u;
        return;
    }
    int e = (blk - 13294) * 256 + threadIdx.x;
    if (e < 384) bcat[e] = (e < 256) ? boff[e] : battn[e - 256];
    if (e < 65536) {
        int n = e >> 8, k = e & 255;
        Wval_t[e] = __float2bfloat16(Wval[k * 256 + n]);
    } else if (e < 163840) {
        int i = e - 65536; int n = i >> 8, k = i & 255;
        float w = (n < 256) ? Woff[k * 256 + n] : Wattn[k * 128 + (n - 256)];
        Wcat_t[i] = __float2bfloat16(w);
    } else if (e < 229376) {
        int i = e - 163840; int n = i >> 8, k = i & 255;
        Wout_t[i] = __float2bfloat16(Wout[k * 256 + n]);
    } else if (e < 491520) {
        int i = e - 229376; int n = i >> 8, k = i & 255;
        W1_t[i] = __float2bfloat16(W1[k * 1024 + n]);
    } else if (e < 753664) {
        int i = e - 491520; int n = i >> 10, k = i & 1023;
        W2_t[i] = __float2bfloat16(W2[k * 256 + n]);
    }
}

// ============ deformable sampling + fused softmax ============
// v layout: [b][head][pix][ch]  (pixel stride 64 B).  4 lanes per (bq,h);
// lane gathers dwordx4 (8 ch).  Table stored k-major so quad lanes hit
// distinct banks on ds_write.
__global__ __launch_bounds__(256)
void sample_kernel(const bf16* __restrict__ v, const bf16* __restrict__ ocat,
                   const float* __restrict__ ref, bf16* __restrict__ samp)
{
    __shared__ int4 tab[64][33];
    const int tid = threadIdx.x;

    // XCD-chunked bijective block swizzle (nwg = 6647, not divisible by 8)
    const int nwg = gridDim.x;
    const int orig = blockIdx.x;
    const int xcd = orig & 7, loc = orig >> 3;
    const int qn = nwg >> 3, rr = nwg & 7;
    const int bid = (xcd < rr ? xcd * (qn + 1) : rr * (qn + 1) + (xcd - rr) * qn) + loc;

    const int ps = tid >> 2;            // pair slot 0..63
    const int qt = tid & 3;             // level index / quad lane
    const int gidx = bid * 64 + ps;
    const int h = gidx & 7, bq = gidx >> 3, b = bq / LTOT;

    {   // phase A: this lane handles level l = qt, points p = l*4+k, k=0..3
        const int l = qt;
        const int W = (l == 0) ? 100 : (l == 1) ? 50 : (l == 2) ? 25 : 13;
        const int S = (l == 0) ? 0 : (l == 1) ? 10000 : (l == 2) ? 12500 : 13125;
        const float fW = (float)W;
        float rx = ref[(size_t)bq * 8 + l * 2 + 0];
        float ry = ref[(size_t)bq * 8 + l * 2 + 1];
        const bf16* ob = ocat + (size_t)bq * 384;
        float lg[4], ox[4], oy[4];
#pragma unroll
        for (int k = 0; k < 4; ++k) {
            ox[k] = b2f(ob[h * 32 + l * 8 + k * 2 + 0]);
            oy[k] = b2f(ob[h * 32 + l * 8 + k * 2 + 1]);
            lg[k] = b2f(ob[256 + h * 16 + l * 4 + k]);
        }
        float m = fmaxf(fmaxf(lg[0], lg[1]), fmaxf(lg[2], lg[3]));
        m = fmaxf(m, __shfl_xor(m, 1));
        m = fmaxf(m, __shfl_xor(m, 2));
        float ev[4]; float s = 0.f;
#pragma unroll
        for (int k = 0; k < 4; ++k) { ev[k] = __expf(lg[k] - m); s += ev[k]; }
        s += __shfl_xor(s, 1);
        s += __shfl_xor(s, 2);
        float inv = 1.f / s;
        // base in bytes: v[b][h][S + pix][*] , 64 B per pixel
        const int base = ((b * 8 + h) * LTOT + S) * 64;
#pragma unroll
        for (int k = 0; k < 4; ++k) {
            float wgt = ev[k] * inv;
            float x = fmaf(rx, fW, ox[k] - 0.5f);
            float y = fmaf(ry, fW, oy[k] - 0.5f);   // H == W at every level
            float x0f = floorf(x), y0f = floorf(y);
            float lx = x - x0f, ly = y - y0f;
            int x0 = (int)x0f, y0 = (int)y0f;
            float tw[4] = {(1.f - lx) * (1.f - ly), lx * (1.f - ly),
                           (1.f - lx) * ly,         lx * ly};
            int o[4]; float w[4];
#pragma unroll
            for (int t = 0; t < 4; ++t) {
                int xi = x0 + (t & 1), yi = y0 + (t >> 1);
                bool ok = (xi >= 0) & (xi < W) & (yi >= 0) & (yi < W);
                o[t] = ok ? base + (yi * W + xi) * 64 : 0;
                w[t] = ok ? wgt * tw[t] : 0.f;
            }
            int e = k * 8 + l * 2;   // k-major: quad lanes -> distinct banks
            tab[ps][e + 0] = make_int4(o[0], __float_as_int(w[0]), o[1], __float_as_int(w[1]));
            tab[ps][e + 1] = make_int4(o[2], __float_as_int(w[2]), o[3], __float_as_int(w[3]));
        }
    }
    __syncthreads();

    const int lofs = qt * 16;
    const char* vc = (const char*)v;
    float al[4] = {0.f, 0.f, 0.f, 0.f}, ah[4] = {0.f, 0.f, 0.f, 0.f};
#pragma unroll 8
    for (int e2 = 0; e2 < 32; ++e2) {
        int4 q = tab[ps][e2];
        uint4 u0 = *(const uint4*)(vc + (size_t)(unsigned)(q.x + lofs));
        uint4 u1 = *(const uint4*)(vc + (size_t)(unsigned)(q.z + lofs));
        float w0 = __int_as_float(q.y), w1 = __int_as_float(q.w);
#pragma unroll
        for (int j = 0; j < 4; ++j) {
            unsigned e0 = ((const unsigned*)&u0)[j];
            unsigned e1 = ((const unsigned*)&u1)[j];
            al[j] += w0 * __uint_as_float(e0 << 16);
            ah[j] += w0 * __uint_as_float(e0);   // hi ch; low-16 mantissa noise
            al[j] += w1 * __uint_as_float(e1 << 16);
            ah[j] += w1 * __uint_as_float(e1);
        }
    }
    union { unsigned u[4]; uint4 q; } r;
#pragma unroll
    for (int j = 0; j < 4; ++j) {
        union { struct { bf16 a, b; } h2; unsigned u; } t2;
        t2.h2.a = __float2bfloat16(al[j]);
        t2.h2.b = __float2bfloat16(ah[j]);
        r.u[j] = t2.u;
    }
    *(uint4*)((char*)samp + (size_t)gidx * 64 + lofs) = r.q;
}

extern "C" void kernel_launch(void* const* d_in, const int* in_sizes, int n_in,
                              void* d_out, int out_size, void* d_ws, size_t ws_size,
                              hipStream_t stream)
{
    const float* src     = (const float*)d_in[0];
    const float* pos     = (const float*)d_in[1];
    const float* ref     = (const float*)d_in[2];
    const float* W_off   = (const float*)d_in[5];
    const float* b_off   = (const float*)d_in[6];
    const float* W_attn  = (const float*)d_in[7];
    const float* b_attn  = (const float*)d_in[8];
    const float* W_val   = (const float*)d_in[9];
    const float* b_val   = (const float*)d_in[10];
    const float* W_out   = (const float*)d_in[11];
    const float* b_out   = (const float*)d_in[12];
    const float* ln_sa_g = (const float*)d_in[13];
    const float* ln_sa_b = (const float*)d_in[14];
    const float* W1      = (const float*)d_in[15];
    const float* b1      = (const float*)d_in[16];
    const float* W2      = (const float*)d_in[17];
    const float* b2      = (const float*)d_in[18];
    const float* ln_ff_g = (const float*)d_in[19];
    const float* ln_ff_b = (const float*)d_in[20];

    char* ws = (char*)d_ws;
    bf16* sb     = (bf16*)(ws);
    bf16* qb     = (bf16*)(ws + 27226112);
    bf16* samp   = (bf16*)(ws + 27226112);
    bf16* vbuf   = (bf16*)(ws + 54452224);
    bf16* ocat   = (bf16*)(ws + 81678336);
    bf16* xb16   = (bf16*)(ws + 122517504);
    bf16* hbuf   = (bf16*)(ws);
    bf16* Wval_t = (bf16*)(ws + 149743616);
    bf16* Wcat_t = (bf16*)(ws + 149874688);
    float* bcat  = (float*)(ws + 150071296);
    bf16* Wout_t = (bf16*)(ws + 150072832);
    bf16* W1_t   = (bf16*)(ws + 150203904);
    bf16* W2_t   = (bf16*)(ws + 150728192);
    float* outf  = (float*)d_out;

    dim3 blk(256);

    // fused elementwise + weight casts (13294 cast blocks + 2944 wcast blocks)
    cast_all<<<dim3(16238), blk, 0, stream>>>(src, pos, sb, qb,
                                              W_val, W_off, W_attn, W_out, W1, W2,
                                              b_off, b_attn,
                                              Wval_t, Wcat_t, Wout_t, W1_t, W2_t, bcat);

    // fused: v = src @ W_val (head-major layout) ; ocat = q @ Wcat + bcat
    mfma_gemm_vc<<<dim3(5, 416), blk, 0, stream>>>(sb, qb, Wval_t, Wcat_t,
                                                   b_val, bcat, vbuf, ocat, ROWS);
    // softmax + sampling (64 pairs per block)
    sample_kernel<<<dim3(ROWS * 8 / 64), blk, 0, stream>>>(vbuf, ocat, ref, samp);
    // x = LN(samp @ W_out + b_out + sb)
    mfma_gemm_ln<bf16><<<dim3(416), dim3(512), 0, stream>>>(
        samp, Wout_t, b_out, sb, xb16, ln_sa_g, ln_sa_b, ROWS, 256);
    // h = relu(x @ W1 + b1)
    mfma_gemm_n<true><<<dim3(8, 416), blk, 0, stream>>>(xb16, W1_t, b1, hbuf, ROWS, 1024, 256);
    // out = LN(h @ W2 + b2 + x)
    mfma_gemm_ln<float><<<dim3(416), dim3(512), 0, stream>>>(
        hbuf, W2_t, b2, xb16, outf, ln_ff_g, ln_ff_b, ROWS, 1024);
}

// Round 6
// 482.893 us; speedup vs baseline: 1.0744x; 1.0744x over previous
//
#include <hip/hip_runtime.h>
#include <hip/hip_bf16.h>

typedef __hip_bfloat16 bf16;
typedef short bf16x8 __attribute__((ext_vector_type(8)));
typedef float f32x4  __attribute__((ext_vector_type(4)));

#define ROWS 53176    // B * L_TOTAL
#define LTOT 13294

__device__ __forceinline__ float b2f(bf16 v) { return __bfloat162float(v); }

__device__ __forceinline__ void gl2lds16(const void* g, void* l) {
    __builtin_amdgcn_global_load_lds(
        (const __attribute__((address_space(1))) unsigned*)g,
        (__attribute__((address_space(3))) unsigned*)l, 16, 0, 0);
}

// ============ narrow MFMA GEMM: 128x128 tile, 2-phase double-buffered ============
template<bool RELU>
__global__ __launch_bounds__(256)
void mfma_gemm_n(const bf16* __restrict__ A, const bf16* __restrict__ Bt,
                 const float* __restrict__ bias, bf16* __restrict__ C,
                 int M, int N, int K)
{
    __shared__ __align__(16) short As[2][128 * 32];
    __shared__ __align__(16) short Bs[2][128 * 32];
    const int tid  = threadIdx.x;
    const int wave = tid >> 6, lane = tid & 63;

    const int nwg  = gridDim.x * gridDim.y;
    const int orig = blockIdx.y * gridDim.x + blockIdx.x;
    const int wgid = ((nwg & 7) == 0) ? ((orig & 7) * (nwg >> 3) + (orig >> 3)) : orig;
    const int bx = wgid % gridDim.x, by = wgid / gridDim.x;

    const int m0 = by * 128, n0 = bx * 128;
    const int lrow = lane >> 2, lcol = lane & 3;
    const int quad = lane >> 4, l15 = lane & 15;

    f32x4 acc[4][4];
#pragma unroll
    for (int i = 0; i < 4; ++i)
#pragma unroll
        for (int j = 0; j < 4; ++j) acc[i][j] = (f32x4){0.f, 0.f, 0.f, 0.f};

    const int wM = (wave >> 1) * 64, wN = (wave & 1) * 64;

    auto stage = [&](int p, int kk) {
#pragma unroll
        for (int q = 0; q < 2; ++q) {
            int rbase = wave * 32 + q * 16;
            int row = rbase + lrow;
            int sw = (lcol * 16) ^ ((row & 3) << 4);     // source pre-swizzle
            gl2lds16((const char*)(A  + (size_t)(m0 + row) * K + kk) + sw, &As[p][rbase * 32]);
            gl2lds16((const char*)(Bt + (size_t)(n0 + row) * K + kk) + sw, &Bs[p][rbase * 32]);
        }
    };

    auto compute = [&](int p) {
        bf16x8 af[4], bfr[4];
#pragma unroll
        for (int i = 0; i < 4; ++i) {
            int row = wM + i * 16 + l15;
            af[i] = *(const bf16x8*)((const char*)&As[p][row * 32]
                                     + ((quad * 16) ^ ((row & 3) << 4)));
        }
#pragma unroll
        for (int j = 0; j < 4; ++j) {
            int row = wN + j * 16 + l15;
            bfr[j] = *(const bf16x8*)((const char*)&Bs[p][row * 32]
                                      + ((quad * 16) ^ ((row & 3) << 4)));
        }
#pragma unroll
        for (int i = 0; i < 4; ++i)
#pragma unroll
            for (int j = 0; j < 4; ++j)
                acc[i][j] = __builtin_amdgcn_mfma_f32_16x16x32_bf16(bfr[j], af[i], acc[i][j], 0, 0, 0);
    };

    stage(0, 0);
    __syncthreads();
    int p = 0;
    for (int kk = 32; kk < K; kk += 32) {
        stage(p ^ 1, kk);
        compute(p);
        __syncthreads();
        p ^= 1;
    }
    compute(p);

    float4 b4[4];
#pragma unroll
    for (int j = 0; j < 4; ++j)
        b4[j] = *(const float4*)&bias[n0 + wN + j * 16 + quad * 4];

#pragma unroll
    for (int i = 0; i < 4; ++i) {
        int gm = m0 + wM + i * 16 + l15;
        if (gm >= M) continue;
#pragma unroll
        for (int j = 0; j < 4; ++j) {
            int gn = n0 + wN + j * 16 + quad * 4;
            union { bf16 h[4]; uint2 u2; } pk;
#pragma unroll
            for (int r = 0; r < 4; ++r) {
                float v = acc[i][j][r] + ((const float*)&b4[j])[r];
                if (RELU) v = fmaxf(v, 0.f);
                pk.h[r] = __float2bfloat16(v);
            }
            *(uint2*)&C[(size_t)gm * N + gn] = pk.u2;
        }
    }
}

// ============ fused val+cat GEMM: bx<2 -> v, bx>=2 -> ocat (linear writes) =====
__global__ __launch_bounds__(256)
void mfma_gemm_vc(const bf16* __restrict__ Av, const bf16* __restrict__ Aq,
                  const bf16* __restrict__ Bv, const bf16* __restrict__ Bc,
                  const float* __restrict__ bv, const float* __restrict__ bc,
                  bf16* __restrict__ Cv, bf16* __restrict__ Cc, int M)
{
    __shared__ __align__(16) short As[2][128 * 32];
    __shared__ __align__(16) short Bs[2][128 * 32];
    const int tid  = threadIdx.x;
    const int wave = tid >> 6, lane = tid & 63;
    const int K = 256;

    const int nwg  = gridDim.x * gridDim.y;   // 5*416 = 2080, div by 8
    const int orig = blockIdx.y * gridDim.x + blockIdx.x;
    const int wgid = ((nwg & 7) == 0) ? ((orig & 7) * (nwg >> 3) + (orig >> 3)) : orig;
    const int bx = wgid % gridDim.x, by = wgid / gridDim.x;

    const bool isval = bx < 2;
    const bf16* A    = isval ? Av : Aq;
    const bf16* Bt   = isval ? Bv : Bc;
    const float* bias = isval ? bv : bc;
    const int n0 = isval ? bx * 128 : (bx - 2) * 128;
    const int Nst = isval ? 256 : 384;
    bf16* C = isval ? Cv : Cc;

    const int m0 = by * 128;
    const int lrow = lane >> 2, lcol = lane & 3;
    const int quad = lane >> 4, l15 = lane & 15;

    f32x4 acc[4][4];
#pragma unroll
    for (int i = 0; i < 4; ++i)
#pragma unroll
        for (int j = 0; j < 4; ++j) acc[i][j] = (f32x4){0.f, 0.f, 0.f, 0.f};

    const int wM = (wave >> 1) * 64, wN = (wave & 1) * 64;

    auto stage = [&](int p, int kk) {
#pragma unroll
        for (int q = 0; q < 2; ++q) {
            int rbase = wave * 32 + q * 16;
            int row = rbase + lrow;
            int sw = (lcol * 16) ^ ((row & 3) << 4);
            gl2lds16((const char*)(A  + (size_t)(m0 + row) * K + kk) + sw, &As[p][rbase * 32]);
            gl2lds16((const char*)(Bt + (size_t)(n0 + row) * K + kk) + sw, &Bs[p][rbase * 32]);
        }
    };

    auto compute = [&](int p) {
        bf16x8 af[4], bfr[4];
#pragma unroll
        for (int i = 0; i < 4; ++i) {
            int row = wM + i * 16 + l15;
            af[i] = *(const bf16x8*)((const char*)&As[p][row * 32]
                                     + ((quad * 16) ^ ((row & 3) << 4)));
        }
#pragma unroll
        for (int j = 0; j < 4; ++j) {
            int row = wN + j * 16 + l15;
            bfr[j] = *(const bf16x8*)((const char*)&Bs[p][row * 32]
                                      + ((quad * 16) ^ ((row & 3) << 4)));
        }
#pragma unroll
        for (int i = 0; i < 4; ++i)
#pragma unroll
            for (int j = 0; j < 4; ++j)
                acc[i][j] = __builtin_amdgcn_mfma_f32_16x16x32_bf16(bfr[j], af[i], acc[i][j], 0, 0, 0);
    };

    stage(0, 0);
    __syncthreads();
    int p = 0;
    for (int kk = 32; kk < K; kk += 32) {
        stage(p ^ 1, kk);
        compute(p);
        __syncthreads();
        p ^= 1;
    }
    compute(p);

    float4 b4[4];
#pragma unroll
    for (int j = 0; j < 4; ++j)
        b4[j] = *(const float4*)&bias[n0 + wN + j * 16 + quad * 4];

#pragma unroll
    for (int i = 0; i < 4; ++i) {
        int gm = m0 + wM + i * 16 + l15;
        if (gm >= M) continue;
#pragma unroll
        for (int j = 0; j < 4; ++j) {
            int gn = n0 + wN + j * 16 + quad * 4;
            union { bf16 h[4]; uint2 u2; } pk;
#pragma unroll
            for (int r = 0; r < 4; ++r)
                pk.h[r] = __float2bfloat16(acc[i][j][r] + ((const float*)&b4[j])[r]);
            *(uint2*)&C[(size_t)gm * Nst + gn] = pk.u2;
        }
    }
}

// ============ wide MFMA GEMM with fused LayerNorm: 128x256, 512 thr, dbuf ======
template<typename OT>
__global__ __launch_bounds__(512)
void mfma_gemm_ln(const bf16* __restrict__ A, const bf16* __restrict__ Bt,
                  const float* __restrict__ bias, const bf16* __restrict__ res,
                  OT* __restrict__ C, const float* __restrict__ gam,
                  const float* __restrict__ bet, int M, int K)
{
    __shared__ __align__(16) short As[2][128 * 32];
    __shared__ __align__(16) short Bs[2][256 * 32];
    __shared__ float rsum[128], rsq[128];
    const int tid  = threadIdx.x;
    const int wave = tid >> 6, lane = tid & 63;
    const int m0 = blockIdx.x * 128;
    const int lrow = lane >> 2, lcol = lane & 3;
    const int quad = lane >> 4, l15 = lane & 15;
    if (tid < 128) { rsum[tid] = 0.f; rsq[tid] = 0.f; }

    f32x4 acc[4][4];
#pragma unroll
    for (int i = 0; i < 4; ++i)
#pragma unroll
        for (int j = 0; j < 4; ++j) acc[i][j] = (f32x4){0.f, 0.f, 0.f, 0.f};

    const int wM = (wave >> 2) * 64, wN = (wave & 3) * 64;

    auto stage = [&](int p, int kk) {
#pragma unroll
        for (int q = 0; q < 3; ++q) {
            int r = wave * 48 + q * 16;
            int sw;
            if (r < 128) {
                int row = r + lrow;
                sw = (lcol * 16) ^ ((row & 3) << 4);
                gl2lds16((const char*)(A + (size_t)(m0 + row) * K + kk) + sw, &As[p][r * 32]);
            } else {
                int rr = r - 128;
                int row = rr + lrow;
                sw = (lcol * 16) ^ ((row & 3) << 4);
                gl2lds16((const char*)(Bt + (size_t)(row) * K + kk) + sw, &Bs[p][rr * 32]);
            }
        }
    };

    auto compute = [&](int p) {
        bf16x8 af[4], bfr[4];
#pragma unroll
        for (int i = 0; i < 4; ++i) {
            int row = wM + i * 16 + l15;
            af[i] = *(const bf16x8*)((const char*)&As[p][row * 32]
                                     + ((quad * 16) ^ ((row & 3) << 4)));
        }
#pragma unroll
        for (int j = 0; j < 4; ++j) {
            int row = wN + j * 16 + l15;
            bfr[j] = *(const bf16x8*)((const char*)&Bs[p][row * 32]
                                      + ((quad * 16) ^ ((row & 3) << 4)));
        }
#pragma unroll
        for (int i = 0; i < 4; ++i)
#pragma unroll
            for (int j = 0; j < 4; ++j)
                acc[i][j] = __builtin_amdgcn_mfma_f32_16x16x32_bf16(bfr[j], af[i], acc[i][j], 0, 0, 0);
    };

    stage(0, 0);
    __syncthreads();
    int p = 0;
    for (int kk = 32; kk < K; kk += 32) {
        stage(p ^ 1, kk);
        compute(p);
        __syncthreads();
        p ^= 1;
    }
    compute(p);

    float4 b4[4], g4[4], be4[4];
#pragma unroll
    for (int j = 0; j < 4; ++j) {
        int gn = wN + j * 16 + quad * 4;
        b4[j]  = *(const float4*)&bias[gn];
        g4[j]  = *(const float4*)&gam[gn];
        be4[j] = *(const float4*)&bet[gn];
    }

    float lsum[4], lsq[4];
#pragma unroll
    for (int i = 0; i < 4; ++i) {
        int gm = m0 + wM + i * 16 + l15;
        lsum[i] = 0.f; lsq[i] = 0.f;
#pragma unroll
        for (int j = 0; j < 4; ++j) {
            int gn = wN + j * 16 + quad * 4;
            float r4[4] = {0.f, 0.f, 0.f, 0.f};
            if (gm < M) {
                uint2 ru = *(const uint2*)&res[(size_t)gm * 256 + gn];
                const bf16* rh = (const bf16*)&ru;
#pragma unroll
                for (int r = 0; r < 4; ++r) r4[r] = b2f(rh[r]);
            }
#pragma unroll
            for (int r = 0; r < 4; ++r) {
                float v = acc[i][j][r] + ((const float*)&b4[j])[r] + r4[r];
                acc[i][j][r] = v;
                lsum[i] += v;
                lsq[i]  += v * v;
            }
        }
#pragma unroll
        for (int mask = 16; mask <= 32; mask <<= 1) {
            lsum[i] += __shfl_xor(lsum[i], mask);
            lsq[i]  += __shfl_xor(lsq[i], mask);
        }
    }
    if (quad == 0) {
#pragma unroll
        for (int i = 0; i < 4; ++i) {
            atomicAdd(&rsum[wM + i * 16 + l15], lsum[i]);
            atomicAdd(&rsq [wM + i * 16 + l15], lsq[i]);
        }
    }
    __syncthreads();

#pragma unroll
    for (int i = 0; i < 4; ++i) {
        int lr = wM + i * 16 + l15;
        int gm = m0 + lr;
        if (gm >= M) continue;
        float mean = rsum[lr] * (1.f / 256.f);
        float var  = rsq[lr] * (1.f / 256.f) - mean * mean;
        float rstd = rsqrtf(fmaxf(var, 0.f) + 1e-5f);
#pragma unroll
        for (int j = 0; j < 4; ++j) {
            int gn = wN + j * 16 + quad * 4;
            if constexpr (sizeof(OT) == 2) {
                union { bf16 h[4]; uint2 u2; } pk;
#pragma unroll
                for (int r = 0; r < 4; ++r)
                    pk.h[r] = __float2bfloat16((acc[i][j][r] - mean) * rstd *
                              ((const float*)&g4[j])[r] + ((const float*)&be4[j])[r]);
                *(uint2*)&((bf16*)C)[(size_t)gm * 256 + gn] = pk.u2;
            } else {
                float4 o;
#pragma unroll
                for (int r = 0; r < 4; ++r)
                    ((float*)&o)[r] = (acc[i][j][r] - mean) * rstd *
                              ((const float*)&g4[j])[r] + ((const float*)&be4[j])[r];
                *(float4*)&((float*)C)[(size_t)gm * 256 + gn] = o;
            }
        }
    }
}

// ============ fused casts: src/pos -> bf16, weights -> bf16 (one dispatch) =====
__global__ __launch_bounds__(256)
void cast_all(const float* __restrict__ s, const float* __restrict__ p,
              bf16* __restrict__ sb, bf16* __restrict__ qb,
              const float* __restrict__ Wval, const float* __restrict__ Woff,
              const float* __restrict__ Wattn, const float* __restrict__ Wout,
              const float* __restrict__ W1, const float* __restrict__ W2,
              const float* __restrict__ boff, const float* __restrict__ battn,
              bf16* __restrict__ Wval_t, bf16* __restrict__ Wcat_t,
              bf16* __restrict__ Wout_t, bf16* __restrict__ W1_t,
              bf16* __restrict__ W2_t, float* __restrict__ bcat)
{
    const int blk = blockIdx.x;
    if (blk < 13294) {
        int i = blk * 256 + threadIdx.x;
        float4 sv = ((const float4*)s)[i];
        float4 pv = ((const float4*)p)[i];
        union { bf16 h[4]; uint2 u; } a, b;
        a.h[0] = __float2bfloat16(sv.x); a.h[1] = __float2bfloat16(sv.y);
        a.h[2] = __float2bfloat16(sv.z); a.h[3] = __float2bfloat16(sv.w);
        b.h[0] = __float2bfloat16(sv.x + pv.x); b.h[1] = __float2bfloat16(sv.y + pv.y);
        b.h[2] = __float2bfloat16(sv.z + pv.z); b.h[3] = __float2bfloat16(sv.w + pv.w);
        ((uint2*)sb)[i] = a.u;
        ((uint2*)qb)[i] = b.u;
        return;
    }
    int e = (blk - 13294) * 256 + threadIdx.x;
    if (e < 384) bcat[e] = (e < 256) ? boff[e] : battn[e - 256];
    if (e < 65536) {
        int n = e >> 8, k = e & 255;
        Wval_t[e] = __float2bfloat16(Wval[k * 256 + n]);
    } else if (e < 163840) {
        int i = e - 65536; int n = i >> 8, k = i & 255;
        float w = (n < 256) ? Woff[k * 256 + n] : Wattn[k * 128 + (n - 256)];
        Wcat_t[i] = __float2bfloat16(w);
    } else if (e < 229376) {
        int i = e - 163840; int n = i >> 8, k = i & 255;
        Wout_t[i] = __float2bfloat16(Wout[k * 256 + n]);
    } else if (e < 491520) {
        int i = e - 229376; int n = i >> 8, k = i & 255;
        W1_t[i] = __float2bfloat16(W1[k * 1024 + n]);
    } else if (e < 753664) {
        int i = e - 491520; int n = i >> 10, k = i & 1023;
        W2_t[i] = __float2bfloat16(W2[k * 256 + n]);
    }
}

// ============ deformable sampling + fused softmax ============
// v layout: [b][pix][head][ch] (512 B/pixel, round-4 proven).  4 lanes per
// (bq,h); lane gathers dwordx4 (8 ch).  Table stored k-major (round-5 proven:
// write-side bank conflicts -> 0).
__global__ __launch_bounds__(256)
void sample_kernel(const bf16* __restrict__ v, const bf16* __restrict__ ocat,
                   const float* __restrict__ ref, bf16* __restrict__ samp)
{
    __shared__ int4 tab[64][33];
    const int tid = threadIdx.x;

    // XCD-chunked bijective block swizzle (nwg = 6647, not divisible by 8)
    const int nwg = gridDim.x;
    const int orig = blockIdx.x;
    const int xcd = orig & 7, loc = orig >> 3;
    const int qn = nwg >> 3, rr = nwg & 7;
    const int bid = (xcd < rr ? xcd * (qn + 1) : rr * (qn + 1) + (xcd - rr) * qn) + loc;

    const int ps = tid >> 2;            // pair slot 0..63
    const int qt = tid & 3;             // level index / quad lane
    const int gidx = bid * 64 + ps;
    const int h = gidx & 7, bq = gidx >> 3, b = bq / LTOT;

    {   // phase A: this lane handles level l = qt, points p = l*4+k, k=0..3
        const int l = qt;
        const int W = (l == 0) ? 100 : (l == 1) ? 50 : (l == 2) ? 25 : 13;
        const int S = (l == 0) ? 0 : (l == 1) ? 10000 : (l == 2) ? 12500 : 13125;
        const float fW = (float)W;
        float rx = ref[(size_t)bq * 8 + l * 2 + 0];
        float ry = ref[(size_t)bq * 8 + l * 2 + 1];
        const bf16* ob = ocat + (size_t)bq * 384;
        float lg[4], ox[4], oy[4];
#pragma unroll
        for (int k = 0; k < 4; ++k) {
            ox[k] = b2f(ob[h * 32 + l * 8 + k * 2 + 0]);
            oy[k] = b2f(ob[h * 32 + l * 8 + k * 2 + 1]);
            lg[k] = b2f(ob[256 + h * 16 + l * 4 + k]);
        }
        float m = fmaxf(fmaxf(lg[0], lg[1]), fmaxf(lg[2], lg[3]));
        m = fmaxf(m, __shfl_xor(m, 1));
        m = fmaxf(m, __shfl_xor(m, 2));
        float ev[4]; float s = 0.f;
#pragma unroll
        for (int k = 0; k < 4; ++k) { ev[k] = __expf(lg[k] - m); s += ev[k]; }
        s += __shfl_xor(s, 1);
        s += __shfl_xor(s, 2);
        float inv = 1.f / s;
        const int base = (b * LTOT + S) * 512 + h * 64;
#pragma unroll
        for (int k = 0; k < 4; ++k) {
            float wgt = ev[k] * inv;
            float x = fmaf(rx, fW, ox[k] - 0.5f);
            float y = fmaf(ry, fW, oy[k] - 0.5f);   // H == W at every level
            float x0f = floorf(x), y0f = floorf(y);
            float lx = x - x0f, ly = y - y0f;
            int x0 = (int)x0f, y0 = (int)y0f;
            float tw[4] = {(1.f - lx) * (1.f - ly), lx * (1.f - ly),
                           (1.f - lx) * ly,         lx * ly};
            int o[4]; float w[4];
#pragma unroll
            for (int t = 0; t < 4; ++t) {
                int xi = x0 + (t & 1), yi = y0 + (t >> 1);
                bool ok = (xi >= 0) & (xi < W) & (yi >= 0) & (yi < W);
                o[t] = ok ? base + (yi * W + xi) * 512 : 0;
                w[t] = ok ? wgt * tw[t] : 0.f;
            }
            int e = k * 8 + l * 2;   // k-major: quad lanes -> distinct banks
            tab[ps][e + 0] = make_int4(o[0], __float_as_int(w[0]), o[1], __float_as_int(w[1]));
            tab[ps][e + 1] = make_int4(o[2], __float_as_int(w[2]), o[3], __float_as_int(w[3]));
        }
    }
    __syncthreads();

    const int lofs = qt * 16;
    const char* vc = (const char*)v;
    float al[4] = {0.f, 0.f, 0.f, 0.f}, ah[4] = {0.f, 0.f, 0.f, 0.f};
#pragma unroll 8
    for (int e2 = 0; e2 < 32; ++e2) {
        int4 q = tab[ps][e2];
        uint4 u0 = *(const uint4*)(vc + (size_t)(unsigned)(q.x + lofs));
        uint4 u1 = *(const uint4*)(vc + (size_t)(unsigned)(q.z + lofs));
        float w0 = __int_as_float(q.y), w1 = __int_as_float(q.w);
#pragma unroll
        for (int j = 0; j < 4; ++j) {
            unsigned e0 = ((const unsigned*)&u0)[j];
            unsigned e1 = ((const unsigned*)&u1)[j];
            al[j] += w0 * __uint_as_float(e0 << 16);
            ah[j] += w0 * __uint_as_float(e0);   // hi ch; low-16 mantissa noise
            al[j] += w1 * __uint_as_float(e1 << 16);
            ah[j] += w1 * __uint_as_float(e1);
        }
    }
    union { unsigned u[4]; uint4 q; } r;
#pragma unroll
    for (int j = 0; j < 4; ++j) {
        union { struct { bf16 a, b; } h2; unsigned u; } t2;
        t2.h2.a = __float2bfloat16(al[j]);
        t2.h2.b = __float2bfloat16(ah[j]);
        r.u[j] = t2.u;
    }
    *(uint4*)((char*)samp + (size_t)gidx * 64 + lofs) = r.q;
}

extern "C" void kernel_launch(void* const* d_in, const int* in_sizes, int n_in,
                              void* d_out, int out_size, void* d_ws, size_t ws_size,
                              hipStream_t stream)
{
    const float* src     = (const float*)d_in[0];
    const float* pos     = (const float*)d_in[1];
    const float* ref     = (const float*)d_in[2];
    const float* W_off   = (const float*)d_in[5];
    const float* b_off   = (const float*)d_in[6];
    const float* W_attn  = (const float*)d_in[7];
    const float* b_attn  = (const float*)d_in[8];
    const float* W_val   = (const float*)d_in[9];
    const float* b_val   = (const float*)d_in[10];
    const float* W_out   = (const float*)d_in[11];
    const float* b_out   = (const float*)d_in[12];
    const float* ln_sa_g = (const float*)d_in[13];
    const float* ln_sa_b = (const float*)d_in[14];
    const float* W1      = (const float*)d_in[15];
    const float* b1      = (const float*)d_in[16];
    const float* W2      = (const float*)d_in[17];
    const float* b2      = (const float*)d_in[18];
    const float* ln_ff_g = (const float*)d_in[19];
    const float* ln_ff_b = (const float*)d_in[20];

    char* ws = (char*)d_ws;
    bf16* sb     = (bf16*)(ws);
    bf16* qb     = (bf16*)(ws + 27226112);
    bf16* samp   = (bf16*)(ws + 27226112);
    bf16* vbuf   = (bf16*)(ws + 54452224);
    bf16* ocat   = (bf16*)(ws + 81678336);
    bf16* xb16   = (bf16*)(ws + 122517504);
    bf16* hbuf   = (bf16*)(ws);
    bf16* Wval_t = (bf16*)(ws + 149743616);
    bf16* Wcat_t = (bf16*)(ws + 149874688);
    float* bcat  = (float*)(ws + 150071296);
    bf16* Wout_t = (bf16*)(ws + 150072832);
    bf16* W1_t   = (bf16*)(ws + 150203904);
    bf16* W2_t   = (bf16*)(ws + 150728192);
    float* outf  = (float*)d_out;

    dim3 blk(256);

    // fused elementwise + weight casts
    cast_all<<<dim3(16238), blk, 0, stream>>>(src, pos, sb, qb,
                                              W_val, W_off, W_attn, W_out, W1, W2,
                                              b_off, b_attn,
                                              Wval_t, Wcat_t, Wout_t, W1_t, W2_t, bcat);

    // fused: v = src @ W_val ; ocat = q @ Wcat + bcat   (linear writes)
    mfma_gemm_vc<<<dim3(5, 416), blk, 0, stream>>>(sb, qb, Wval_t, Wcat_t,
                                                   b_val, bcat, vbuf, ocat, ROWS);
    // softmax + sampling (64 pairs per block)
    sample_kernel<<<dim3(ROWS * 8 / 64), blk, 0, stream>>>(vbuf, ocat, ref, samp);
    // x = LN(samp @ W_out + b_out + sb)
    mfma_gemm_ln<bf16><<<dim3(416), dim3(512), 0, stream>>>(
        samp, Wout_t, b_out, sb, xb16, ln_sa_g, ln_sa_b, ROWS, 256);
    // h = relu(x @ W1 + b1)
    mfma_gemm_n<true><<<dim3(8, 416), blk, 0, stream>>>(xb16, W1_t, b1, hbuf, ROWS, 1024, 256);
    // out = LN(h @ W2 + b2 + x)
    mfma_gemm_ln<float><<<dim3(416), dim3(512), 0, stream>>>(
        hbuf, W2_t, b2, xb16, outf, ln_ff_g, ln_ff_b, ROWS, 1024);
}

// Round 7
// 459.754 us; speedup vs baseline: 1.1284x; 1.0503x over previous
//
#include <hip/hip_runtime.h>
#include <hip/hip_bf16.h>

typedef __hip_bfloat16 bf16;
typedef short bf16x8 __attribute__((ext_vector_type(8)));
typedef float f32x4  __attribute__((ext_vector_type(4)));

#define ROWS 53176    // B * L_TOTAL
#define LTOT 13294

__device__ __forceinline__ float b2f(bf16 v) { return __bfloat162float(v); }

__device__ __forceinline__ void gl2lds16(const void* g, void* l) {
    __builtin_amdgcn_global_load_lds(
        (const __attribute__((address_space(1))) unsigned*)g,
        (__attribute__((address_space(3))) unsigned*)l, 16, 0, 0);
}

// ============ narrow MFMA GEMM: 128x128 tile, 2-phase double-buffered ============
template<bool RELU>
__global__ __launch_bounds__(256)
void mfma_gemm_n(const bf16* __restrict__ A, const bf16* __restrict__ Bt,
                 const float* __restrict__ bias, bf16* __restrict__ C,
                 int M, int N, int K)
{
    __shared__ __align__(16) short As[2][128 * 32];
    __shared__ __align__(16) short Bs[2][128 * 32];
    const int tid  = threadIdx.x;
    const int wave = tid >> 6, lane = tid & 63;

    const int nwg  = gridDim.x * gridDim.y;
    const int orig = blockIdx.y * gridDim.x + blockIdx.x;
    const int wgid = ((nwg & 7) == 0) ? ((orig & 7) * (nwg >> 3) + (orig >> 3)) : orig;
    const int bx = wgid % gridDim.x, by = wgid / gridDim.x;

    const int m0 = by * 128, n0 = bx * 128;
    const int lrow = lane >> 2, lcol = lane & 3;
    const int quad = lane >> 4, l15 = lane & 15;

    f32x4 acc[4][4];
#pragma unroll
    for (int i = 0; i < 4; ++i)
#pragma unroll
        for (int j = 0; j < 4; ++j) acc[i][j] = (f32x4){0.f, 0.f, 0.f, 0.f};

    const int wM = (wave >> 1) * 64, wN = (wave & 1) * 64;

    auto stage = [&](int p, int kk) {
#pragma unroll
        for (int q = 0; q < 2; ++q) {
            int rbase = wave * 32 + q * 16;
            int row = rbase + lrow;
            int sw = (lcol * 16) ^ ((row & 3) << 4);     // source pre-swizzle
            gl2lds16((const char*)(A  + (size_t)(m0 + row) * K + kk) + sw, &As[p][rbase * 32]);
            gl2lds16((const char*)(Bt + (size_t)(n0 + row) * K + kk) + sw, &Bs[p][rbase * 32]);
        }
    };

    auto compute = [&](int p) {
        bf16x8 af[4], bfr[4];
#pragma unroll
        for (int i = 0; i < 4; ++i) {
            int row = wM + i * 16 + l15;
            af[i] = *(const bf16x8*)((const char*)&As[p][row * 32]
                                     + ((quad * 16) ^ ((row & 3) << 4)));
        }
#pragma unroll
        for (int j = 0; j < 4; ++j) {
            int row = wN + j * 16 + l15;
            bfr[j] = *(const bf16x8*)((const char*)&Bs[p][row * 32]
                                      + ((quad * 16) ^ ((row & 3) << 4)));
        }
#pragma unroll
        for (int i = 0; i < 4; ++i)
#pragma unroll
            for (int j = 0; j < 4; ++j)
                acc[i][j] = __builtin_amdgcn_mfma_f32_16x16x32_bf16(bfr[j], af[i], acc[i][j], 0, 0, 0);
    };

    stage(0, 0);
    __syncthreads();
    int p = 0;
    for (int kk = 32; kk < K; kk += 32) {
        stage(p ^ 1, kk);
        compute(p);
        __syncthreads();
        p ^= 1;
    }
    compute(p);

    float4 b4[4];
#pragma unroll
    for (int j = 0; j < 4; ++j)
        b4[j] = *(const float4*)&bias[n0 + wN + j * 16 + quad * 4];

#pragma unroll
    for (int i = 0; i < 4; ++i) {
        int gm = m0 + wM + i * 16 + l15;
        if (gm >= M) continue;
#pragma unroll
        for (int j = 0; j < 4; ++j) {
            int gn = n0 + wN + j * 16 + quad * 4;
            union { bf16 h[4]; uint2 u2; } pk;
#pragma unroll
            for (int r = 0; r < 4; ++r) {
                float v = acc[i][j][r] + ((const float*)&b4[j])[r];
                if (RELU) v = fmaxf(v, 0.f);
                pk.h[r] = __float2bfloat16(v);
            }
            *(uint2*)&C[(size_t)gm * N + gn] = pk.u2;
        }
    }
}

// ============ fused val+cat GEMM: bx<2 -> v, bx>=2 -> ocat (linear writes) =====
__global__ __launch_bounds__(256)
void mfma_gemm_vc(const bf16* __restrict__ Av, const bf16* __restrict__ Aq,
                  const bf16* __restrict__ Bv, const bf16* __restrict__ Bc,
                  const float* __restrict__ bv, const float* __restrict__ bc,
                  bf16* __restrict__ Cv, bf16* __restrict__ Cc, int M)
{
    __shared__ __align__(16) short As[2][128 * 32];
    __shared__ __align__(16) short Bs[2][128 * 32];
    const int tid  = threadIdx.x;
    const int wave = tid >> 6, lane = tid & 63;
    const int K = 256;

    const int nwg  = gridDim.x * gridDim.y;   // 5*416 = 2080, div by 8
    const int orig = blockIdx.y * gridDim.x + blockIdx.x;
    const int wgid = ((nwg & 7) == 0) ? ((orig & 7) * (nwg >> 3) + (orig >> 3)) : orig;
    const int bx = wgid % gridDim.x, by = wgid / gridDim.x;

    const bool isval = bx < 2;
    const bf16* A    = isval ? Av : Aq;
    const bf16* Bt   = isval ? Bv : Bc;
    const float* bias = isval ? bv : bc;
    const int n0 = isval ? bx * 128 : (bx - 2) * 128;
    const int Nst = isval ? 256 : 384;
    bf16* C = isval ? Cv : Cc;

    const int m0 = by * 128;
    const int lrow = lane >> 2, lcol = lane & 3;
    const int quad = lane >> 4, l15 = lane & 15;

    f32x4 acc[4][4];
#pragma unroll
    for (int i = 0; i < 4; ++i)
#pragma unroll
        for (int j = 0; j < 4; ++j) acc[i][j] = (f32x4){0.f, 0.f, 0.f, 0.f};

    const int wM = (wave >> 1) * 64, wN = (wave & 1) * 64;

    auto stage = [&](int p, int kk) {
#pragma unroll
        for (int q = 0; q < 2; ++q) {
            int rbase = wave * 32 + q * 16;
            int row = rbase + lrow;
            int sw = (lcol * 16) ^ ((row & 3) << 4);
            gl2lds16((const char*)(A  + (size_t)(m0 + row) * K + kk) + sw, &As[p][rbase * 32]);
            gl2lds16((const char*)(Bt + (size_t)(n0 + row) * K + kk) + sw, &Bs[p][rbase * 32]);
        }
    };

    auto compute = [&](int p) {
        bf16x8 af[4], bfr[4];
#pragma unroll
        for (int i = 0; i < 4; ++i) {
            int row = wM + i * 16 + l15;
            af[i] = *(const bf16x8*)((const char*)&As[p][row * 32]
                                     + ((quad * 16) ^ ((row & 3) << 4)));
        }
#pragma unroll
        for (int j = 0; j < 4; ++j) {
            int row = wN + j * 16 + l15;
            bfr[j] = *(const bf16x8*)((const char*)&Bs[p][row * 32]
                                      + ((quad * 16) ^ ((row & 3) << 4)));
        }
#pragma unroll
        for (int i = 0; i < 4; ++i)
#pragma unroll
            for (int j = 0; j < 4; ++j)
                acc[i][j] = __builtin_amdgcn_mfma_f32_16x16x32_bf16(bfr[j], af[i], acc[i][j], 0, 0, 0);
    };

    stage(0, 0);
    __syncthreads();
    int p = 0;
    for (int kk = 32; kk < K; kk += 32) {
        stage(p ^ 1, kk);
        compute(p);
        __syncthreads();
        p ^= 1;
    }
    compute(p);

    float4 b4[4];
#pragma unroll
    for (int j = 0; j < 4; ++j)
        b4[j] = *(const float4*)&bias[n0 + wN + j * 16 + quad * 4];

#pragma unroll
    for (int i = 0; i < 4; ++i) {
        int gm = m0 + wM + i * 16 + l15;
        if (gm >= M) continue;
#pragma unroll
        for (int j = 0; j < 4; ++j) {
            int gn = n0 + wN + j * 16 + quad * 4;
            union { bf16 h[4]; uint2 u2; } pk;
#pragma unroll
            for (int r = 0; r < 4; ++r)
                pk.h[r] = __float2bfloat16(acc[i][j][r] + ((const float*)&b4[j])[r]);
            *(uint2*)&C[(size_t)gm * Nst + gn] = pk.u2;
        }
    }
}

// ============ wide MFMA GEMM with fused LayerNorm: 128x256, 512 thr, dbuf ======
template<typename OT>
__global__ __launch_bounds__(512)
void mfma_gemm_ln(const bf16* __restrict__ A, const bf16* __restrict__ Bt,
                  const float* __restrict__ bias, const bf16* __restrict__ res,
                  OT* __restrict__ C, const float* __restrict__ gam,
                  const float* __restrict__ bet, int M, int K)
{
    __shared__ __align__(16) short As[2][128 * 32];
    __shared__ __align__(16) short Bs[2][256 * 32];
    __shared__ float rsum[128], rsq[128];
    const int tid  = threadIdx.x;
    const int wave = tid >> 6, lane = tid & 63;
    const int m0 = blockIdx.x * 128;
    const int lrow = lane >> 2, lcol = lane & 3;
    const int quad = lane >> 4, l15 = lane & 15;
    if (tid < 128) { rsum[tid] = 0.f; rsq[tid] = 0.f; }

    f32x4 acc[4][4];
#pragma unroll
    for (int i = 0; i < 4; ++i)
#pragma unroll
        for (int j = 0; j < 4; ++j) acc[i][j] = (f32x4){0.f, 0.f, 0.f, 0.f};

    const int wM = (wave >> 2) * 64, wN = (wave & 3) * 64;

    auto stage = [&](int p, int kk) {
#pragma unroll
        for (int q = 0; q < 3; ++q) {
            int r = wave * 48 + q * 16;
            int sw;
            if (r < 128) {
                int row = r + lrow;
                sw = (lcol * 16) ^ ((row & 3) << 4);
                gl2lds16((const char*)(A + (size_t)(m0 + row) * K + kk) + sw, &As[p][r * 32]);
            } else {
                int rr = r - 128;
                int row = rr + lrow;
                sw = (lcol * 16) ^ ((row & 3) << 4);
                gl2lds16((const char*)(Bt + (size_t)(row) * K + kk) + sw, &Bs[p][rr * 32]);
            }
        }
    };

    auto compute = [&](int p) {
        bf16x8 af[4], bfr[4];
#pragma unroll
        for (int i = 0; i < 4; ++i) {
            int row = wM + i * 16 + l15;
            af[i] = *(const bf16x8*)((const char*)&As[p][row * 32]
                                     + ((quad * 16) ^ ((row & 3) << 4)));
        }
#pragma unroll
        for (int j = 0; j < 4; ++j) {
            int row = wN + j * 16 + l15;
            bfr[j] = *(const bf16x8*)((const char*)&Bs[p][row * 32]
                                      + ((quad * 16) ^ ((row & 3) << 4)));
        }
#pragma unroll
        for (int i = 0; i < 4; ++i)
#pragma unroll
            for (int j = 0; j < 4; ++j)
                acc[i][j] = __builtin_amdgcn_mfma_f32_16x16x32_bf16(bfr[j], af[i], acc[i][j], 0, 0, 0);
    };

    stage(0, 0);
    __syncthreads();
    int p = 0;
    for (int kk = 32; kk < K; kk += 32) {
        stage(p ^ 1, kk);
        compute(p);
        __syncthreads();
        p ^= 1;
    }
    compute(p);

    float4 b4[4], g4[4], be4[4];
#pragma unroll
    for (int j = 0; j < 4; ++j) {
        int gn = wN + j * 16 + quad * 4;
        b4[j]  = *(const float4*)&bias[gn];
        g4[j]  = *(const float4*)&gam[gn];
        be4[j] = *(const float4*)&bet[gn];
    }

    float lsum[4], lsq[4];
#pragma unroll
    for (int i = 0; i < 4; ++i) {
        int gm = m0 + wM + i * 16 + l15;
        lsum[i] = 0.f; lsq[i] = 0.f;
#pragma unroll
        for (int j = 0; j < 4; ++j) {
            int gn = wN + j * 16 + quad * 4;
            float r4[4] = {0.f, 0.f, 0.f, 0.f};
            if (gm < M) {
                uint2 ru = *(const uint2*)&res[(size_t)gm * 256 + gn];
                const bf16* rh = (const bf16*)&ru;
#pragma unroll
                for (int r = 0; r < 4; ++r) r4[r] = b2f(rh[r]);
            }
#pragma unroll
            for (int r = 0; r < 4; ++r) {
                float v = acc[i][j][r] + ((const float*)&b4[j])[r] + r4[r];
                acc[i][j][r] = v;
                lsum[i] += v;
                lsq[i]  += v * v;
            }
        }
#pragma unroll
        for (int mask = 16; mask <= 32; mask <<= 1) {
            lsum[i] += __shfl_xor(lsum[i], mask);
            lsq[i]  += __shfl_xor(lsq[i], mask);
        }
    }
    if (quad == 0) {
#pragma unroll
        for (int i = 0; i < 4; ++i) {
            atomicAdd(&rsum[wM + i * 16 + l15], lsum[i]);
            atomicAdd(&rsq [wM + i * 16 + l15], lsq[i]);
        }
    }
    __syncthreads();

#pragma unroll
    for (int i = 0; i < 4; ++i) {
        int lr = wM + i * 16 + l15;
        int gm = m0 + lr;
        if (gm >= M) continue;
        float mean = rsum[lr] * (1.f / 256.f);
        float var  = rsq[lr] * (1.f / 256.f) - mean * mean;
        float rstd = rsqrtf(fmaxf(var, 0.f) + 1e-5f);
#pragma unroll
        for (int j = 0; j < 4; ++j) {
            int gn = wN + j * 16 + quad * 4;
            if constexpr (sizeof(OT) == 2) {
                union { bf16 h[4]; uint2 u2; } pk;
#pragma unroll
                for (int r = 0; r < 4; ++r)
                    pk.h[r] = __float2bfloat16((acc[i][j][r] - mean) * rstd *
                              ((const float*)&g4[j])[r] + ((const float*)&be4[j])[r]);
                *(uint2*)&((bf16*)C)[(size_t)gm * 256 + gn] = pk.u2;
            } else {
                float4 o;
#pragma unroll
                for (int r = 0; r < 4; ++r)
                    ((float*)&o)[r] = (acc[i][j][r] - mean) * rstd *
                              ((const float*)&g4[j])[r] + ((const float*)&be4[j])[r];
                *(float4*)&((float*)C)[(size_t)gm * 256 + gn] = o;
            }
        }
    }
}

// ============ fused casts: src/pos -> bf16, weights -> bf16 (one dispatch) =====
__global__ __launch_bounds__(256)
void cast_all(const float* __restrict__ s, const float* __restrict__ p,
              bf16* __restrict__ sb, bf16* __restrict__ qb,
              const float* __restrict__ Wval, const float* __restrict__ Woff,
              const float* __restrict__ Wattn, const float* __restrict__ Wout,
              const float* __restrict__ W1, const float* __restrict__ W2,
              const float* __restrict__ boff, const float* __restrict__ battn,
              bf16* __restrict__ Wval_t, bf16* __restrict__ Wcat_t,
              bf16* __restrict__ Wout_t, bf16* __restrict__ W1_t,
              bf16* __restrict__ W2_t, float* __restrict__ bcat)
{
    const int blk = blockIdx.x;
    if (blk < 13294) {
        int i = blk * 256 + threadIdx.x;
        float4 sv = ((const float4*)s)[i];
        float4 pv = ((const float4*)p)[i];
        union { bf16 h[4]; uint2 u; } a, b;
        a.h[0] = __float2bfloat16(sv.x); a.h[1] = __float2bfloat16(sv.y);
        a.h[2] = __float2bfloat16(sv.z); a.h[3] = __float2bfloat16(sv.w);
        b.h[0] = __float2bfloat16(sv.x + pv.x); b.h[1] = __float2bfloat16(sv.y + pv.y);
        b.h[2] = __float2bfloat16(sv.z + pv.z); b.h[3] = __float2bfloat16(sv.w + pv.w);
        ((uint2*)sb)[i] = a.u;
        ((uint2*)qb)[i] = b.u;
        return;
    }
    int e = (blk - 13294) * 256 + threadIdx.x;
    if (e < 384) bcat[e] = (e < 256) ? boff[e] : battn[e - 256];
    if (e < 65536) {
        int n = e >> 8, k = e & 255;
        Wval_t[e] = __float2bfloat16(Wval[k * 256 + n]);
    } else if (e < 163840) {
        int i = e - 65536; int n = i >> 8, k = i & 255;
        float w = (n < 256) ? Woff[k * 256 + n] : Wattn[k * 128 + (n - 256)];
        Wcat_t[i] = __float2bfloat16(w);
    } else if (e < 229376) {
        int i = e - 163840; int n = i >> 8, k = i & 255;
        Wout_t[i] = __float2bfloat16(Wout[k * 256 + n]);
    } else if (e < 491520) {
        int i = e - 229376; int n = i >> 8, k = i & 255;
        W1_t[i] = __float2bfloat16(W1[k * 1024 + n]);
    } else if (e < 753664) {
        int i = e - 491520; int n = i >> 10, k = i & 1023;
        W2_t[i] = __float2bfloat16(W2[k * 256 + n]);
    }
}

// ============ deformable sampling + fused softmax ============
// v layout: [b][pix][head][ch] (512 B/pixel).  4 lanes per (bq,h); lane
// gathers dwordx4 (8 ch).  Table: SEMANTIC order is level-major (round-4
// proven traversal => L2-temporal locality); PHYSICAL slot is rotation-
// swizzled (slot = l*8 + ((rem + 2l) & 7)) so quad lanes write distinct
// bank groups (round-6 proven: write conflicts -> 0).  Reads are broadcast,
// so the read-side permutation is free.
__global__ __launch_bounds__(256)
void sample_kernel(const bf16* __restrict__ v, const bf16* __restrict__ ocat,
                   const float* __restrict__ ref, bf16* __restrict__ samp)
{
    __shared__ int4 tab[64][33];
    const int tid = threadIdx.x;

    // XCD-chunked bijective block swizzle (nwg = 6647, not divisible by 8)
    const int nwg = gridDim.x;
    const int orig = blockIdx.x;
    const int xcd = orig & 7, loc = orig >> 3;
    const int qn = nwg >> 3, rr = nwg & 7;
    const int bid = (xcd < rr ? xcd * (qn + 1) : rr * (qn + 1) + (xcd - rr) * qn) + loc;

    const int ps = tid >> 2;            // pair slot 0..63
    const int qt = tid & 3;             // level index / quad lane
    const int gidx = bid * 64 + ps;
    const int h = gidx & 7, bq = gidx >> 3, b = bq / LTOT;

    {   // phase A: this lane handles level l = qt, points p = l*4+k, k=0..3
        const int l = qt;
        const int W = (l == 0) ? 100 : (l == 1) ? 50 : (l == 2) ? 25 : 13;
        const int S = (l == 0) ? 0 : (l == 1) ? 10000 : (l == 2) ? 12500 : 13125;
        const float fW = (float)W;
        float rx = ref[(size_t)bq * 8 + l * 2 + 0];
        float ry = ref[(size_t)bq * 8 + l * 2 + 1];
        const bf16* ob = ocat + (size_t)bq * 384;
        float lg[4], ox[4], oy[4];
#pragma unroll
        for (int k = 0; k < 4; ++k) {
            ox[k] = b2f(ob[h * 32 + l * 8 + k * 2 + 0]);
            oy[k] = b2f(ob[h * 32 + l * 8 + k * 2 + 1]);
            lg[k] = b2f(ob[256 + h * 16 + l * 4 + k]);
        }
        float m = fmaxf(fmaxf(lg[0], lg[1]), fmaxf(lg[2], lg[3]));
        m = fmaxf(m, __shfl_xor(m, 1));
        m = fmaxf(m, __shfl_xor(m, 2));
        float ev[4]; float s = 0.f;
#pragma unroll
        for (int k = 0; k < 4; ++k) { ev[k] = __expf(lg[k] - m); s += ev[k]; }
        s += __shfl_xor(s, 1);
        s += __shfl_xor(s, 2);
        float inv = 1.f / s;
        const int base = (b * LTOT + S) * 512 + h * 64;
#pragma unroll
        for (int k = 0; k < 4; ++k) {
            float wgt = ev[k] * inv;
            float x = fmaf(rx, fW, ox[k] - 0.5f);
            float y = fmaf(ry, fW, oy[k] - 0.5f);   // H == W at every level
            float x0f = floorf(x), y0f = floorf(y);
            float lx = x - x0f, ly = y - y0f;
            int x0 = (int)x0f, y0 = (int)y0f;
            float tw[4] = {(1.f - lx) * (1.f - ly), lx * (1.f - ly),
                           (1.f - lx) * ly,         lx * ly};
            int o[4]; float w[4];
#pragma unroll
            for (int t = 0; t < 4; ++t) {
                int xi = x0 + (t & 1), yi = y0 + (t >> 1);
                bool ok = (xi >= 0) & (xi < W) & (yi >= 0) & (yi < W);
                o[t] = ok ? base + (yi * W + xi) * 512 : 0;
                w[t] = ok ? wgt * tw[t] : 0.f;
            }
            // physical slot = l*8 + ((rem + 2l) & 7), rem = k*2 + t2
            int s0 = l * 8 + ((k * 2 + 0 + l * 2) & 7);
            int s1 = l * 8 + ((k * 2 + 1 + l * 2) & 7);
            tab[ps][s0] = make_int4(o[0], __float_as_int(w[0]), o[1], __float_as_int(w[1]));
            tab[ps][s1] = make_int4(o[2], __float_as_int(w[2]), o[3], __float_as_int(w[3]));
        }
    }
    __syncthreads();

    const int lofs = qt * 16;
    const char* vc = (const char*)v;
    float al[4] = {0.f, 0.f, 0.f, 0.f}, ah[4] = {0.f, 0.f, 0.f, 0.f};
#pragma unroll 8
    for (int e2 = 0; e2 < 32; ++e2) {
        // semantic order: level-major (e2 = l*8 + rem); fetch swizzled slot
        int pe = (e2 & 24) | ((e2 + ((e2 >> 3) << 1)) & 7);
        int4 q = tab[ps][pe];
        uint4 u0 = *(const uint4*)(vc + (size_t)(unsigned)(q.x + lofs));
        uint4 u1 = *(const uint4*)(vc + (size_t)(unsigned)(q.z + lofs));
        float w0 = __int_as_float(q.y), w1 = __int_as_float(q.w);
#pragma unroll
        for (int j = 0; j < 4; ++j) {
            unsigned e0 = ((const unsigned*)&u0)[j];
            unsigned e1 = ((const unsigned*)&u1)[j];
            al[j] += w0 * __uint_as_float(e0 << 16);
            ah[j] += w0 * __uint_as_float(e0);   // hi ch; low-16 mantissa noise
            al[j] += w1 * __uint_as_float(e1 << 16);
            ah[j] += w1 * __uint_as_float(e1);
        }
    }
    union { unsigned u[4]; uint4 q; } r;
#pragma unroll
    for (int j = 0; j < 4; ++j) {
        union { struct { bf16 a, b; } h2; unsigned u; } t2;
        t2.h2.a = __float2bfloat16(al[j]);
        t2.h2.b = __float2bfloat16(ah[j]);
        r.u[j] = t2.u;
    }
    *(uint4*)((char*)samp + (size_t)gidx * 64 + lofs) = r.q;
}

extern "C" void kernel_launch(void* const* d_in, const int* in_sizes, int n_in,
                              void* d_out, int out_size, void* d_ws, size_t ws_size,
                              hipStream_t stream)
{
    const float* src     = (const float*)d_in[0];
    const float* pos     = (const float*)d_in[1];
    const float* ref     = (const float*)d_in[2];
    const float* W_off   = (const float*)d_in[5];
    const float* b_off   = (const float*)d_in[6];
    const float* W_attn  = (const float*)d_in[7];
    const float* b_attn  = (const float*)d_in[8];
    const float* W_val   = (const float*)d_in[9];
    const float* b_val   = (const float*)d_in[10];
    const float* W_out   = (const float*)d_in[11];
    const float* b_out   = (const float*)d_in[12];
    const float* ln_sa_g = (const float*)d_in[13];
    const float* ln_sa_b = (const float*)d_in[14];
    const float* W1      = (const float*)d_in[15];
    const float* b1      = (const float*)d_in[16];
    const float* W2      = (const float*)d_in[17];
    const float* b2      = (const float*)d_in[18];
    const float* ln_ff_g = (const float*)d_in[19];
    const float* ln_ff_b = (const float*)d_in[20];

    char* ws = (char*)d_ws;
    bf16* sb     = (bf16*)(ws);
    bf16* qb     = (bf16*)(ws + 27226112);
    bf16* samp   = (bf16*)(ws + 27226112);
    bf16* vbuf   = (bf16*)(ws + 54452224);
    bf16* ocat   = (bf16*)(ws + 81678336);
    bf16* xb16   = (bf16*)(ws + 122517504);
    bf16* hbuf   = (bf16*)(ws);
    bf16* Wval_t = (bf16*)(ws + 149743616);
    bf16* Wcat_t = (bf16*)(ws + 149874688);
    float* bcat  = (float*)(ws + 150071296);
    bf16* Wout_t = (bf16*)(ws + 150072832);
    bf16* W1_t   = (bf16*)(ws + 150203904);
    bf16* W2_t   = (bf16*)(ws + 150728192);
    float* outf  = (float*)d_out;

    dim3 blk(256);

    // fused elementwise + weight casts
    cast_all<<<dim3(16238), blk, 0, stream>>>(src, pos, sb, qb,
                                              W_val, W_off, W_attn, W_out, W1, W2,
                                              b_off, b_attn,
                                              Wval_t, Wcat_t, Wout_t, W1_t, W2_t, bcat);

    // fused: v = src @ W_val ; ocat = q @ Wcat + bcat   (linear writes)
    mfma_gemm_vc<<<dim3(5, 416), blk, 0, stream>>>(sb, qb, Wval_t, Wcat_t,
                                                   b_val, bcat, vbuf, ocat, ROWS);
    // softmax + sampling (64 pairs per block)
    sample_kernel<<<dim3(ROWS * 8 / 64), blk, 0, stream>>>(vbuf, ocat, ref, samp);
    // x = LN(samp @ W_out + b_out + sb)
    mfma_gemm_ln<bf16><<<dim3(416), dim3(512), 0, stream>>>(
        samp, Wout_t, b_out, sb, xb16, ln_sa_g, ln_sa_b, ROWS, 256);
    // h = relu(x @ W1 + b1)
    mfma_gemm_n<true><<<dim3(8, 416), blk, 0, stream>>>(xb16, W1_t, b1, hbuf, ROWS, 1024, 256);
    // out = LN(h @ W2 + b2 + x)
    mfma_gemm_ln<float><<<dim3(416), dim3(512), 0, stream>>>(
        hbuf, W2_t, b2, xb16, outf, ln_ff_g, ln_ff_b, ROWS, 1024);
}